// Round 5
// baseline (396.061 us; speedup 1.0000x reference)
//
#include <hip/hip_runtime.h>

typedef __bf16 bf16x8 __attribute__((ext_vector_type(8)));
typedef __bf16 bf16x4 __attribute__((ext_vector_type(4)));
typedef float  f32x4  __attribute__((ext_vector_type(4)));

// ws layout (bf16 elements), all in MFMA b-fragment order [kstep][ntile][lane][8]
#define OFF_W1  0        // 20 ksteps * 16 nt * 512  = 163840   (s_w1 640x256)
#define OFF_W2  163840   //  8 * 16 * 512            =  65536   (s_w2 256x256)
#define OFF_WQ  229376   //  8 *  8 * 512            =  32768   (qd|qe interleaved 256x128)
#define OFF_WH1 262144   //  1 *  8 * 512            =   4096   (h_w1 10->32 zero-pad x128)
#define OFF_WH2 266240   //  4 *  8 * 512            =  16384   (h_w2 128x128)
#define WS_ELEMS 282624

__global__ __launch_bounds__(256) void prep_kernel(
    const float* __restrict__ s_w1, const float* __restrict__ s_w2,
    const float* __restrict__ qd_w, const float* __restrict__ qe_w,
    const float* __restrict__ h_w1, const float* __restrict__ h_w2,
    __bf16* __restrict__ wsb)
{
  int idx = blockIdx.x * 256 + threadIdx.x;
  if (idx >= WS_ELEMS) return;
  float val = 0.f;
  if (idx < OFF_W2) {                       // W1: K=640, N=256
    int t = idx;
    int j = t & 7, l = (t >> 3) & 63, rest = t >> 9;
    int nt = rest & 15, ks = rest >> 4;
    int k = ks * 32 + (l >> 4) * 8 + j, n = nt * 16 + (l & 15);
    val = s_w1[k * 256 + n];
  } else if (idx < OFF_WQ) {                // W2: K=256, N=256
    int t = idx - OFF_W2;
    int j = t & 7, l = (t >> 3) & 63, rest = t >> 9;
    int nt = rest & 15, ks = rest >> 4;
    int k = ks * 32 + (l >> 4) * 8 + j, n = nt * 16 + (l & 15);
    val = s_w2[k * 256 + n];
  } else if (idx < OFF_WH1) {               // Wq: K=256, N=128, n = 2a+sel
    int t = idx - OFF_WQ;
    int j = t & 7, l = (t >> 3) & 63, rest = t >> 9;
    int nt = rest & 7, ks = rest >> 3;
    int k = ks * 32 + (l >> 4) * 8 + j, n = nt * 16 + (l & 15);
    int a = n >> 1;
    val = (n & 1) ? qe_w[k * 64 + a] : qd_w[k * 64 + a];
  } else if (idx < OFF_WH2) {               // Wh1: K=10 padded to 32, N=128
    int t = idx - OFF_WH1;
    int j = t & 7, l = (t >> 3) & 63, rest = t >> 9;
    int nt = rest & 7;
    int k = (l >> 4) * 8 + j, n = nt * 16 + (l & 15);
    val = (k < 10) ? h_w1[k * 128 + n] : 0.f;
  } else {                                  // Wh2: K=128, N=128
    int t = idx - OFF_WH2;
    int j = t & 7, l = (t >> 3) & 63, rest = t >> 9;
    int nt = rest & 7, ks = rest >> 3;
    int k = ks * 32 + (l >> 4) * 8 + j, n = nt * 16 + (l & 15);
    val = h_w2[k * 128 + n];
  }
  wsb[idx] = (__bf16)val;
}

// MT=2: wave owns ntiles [nt0, nt0+NTW) x both 16-row mtiles; B fragment loaded
// once per kstep, reused across the 2 mtiles (halves B L2-stream per row).
template<int KSTEPS, int NT_TOT, int NTW>
__device__ __forceinline__ void run_gemm2(const __bf16* A, int astride,
    const bf16x8* __restrict__ Bsw, int nt0, int lane, f32x4 acc[2][NTW])
{
  const int quad = lane >> 4, ln = lane & 15;
  const __bf16* ar = A + ln * astride + quad * 8;
  bf16x8 bcur[NTW];
#pragma unroll
  for (int i = 0; i < NTW; ++i) bcur[i] = Bsw[(nt0 + i) * 64 + lane];
#pragma unroll
  for (int ks = 0; ks < KSTEPS; ++ks) {
    bf16x8 bnxt[NTW];
    if (ks + 1 < KSTEPS) {
#pragma unroll
      for (int i = 0; i < NTW; ++i)
        bnxt[i] = Bsw[((ks + 1) * NT_TOT + nt0 + i) * 64 + lane];
    }
    bf16x8 a0 = *(const bf16x8*)(ar + ks * 32);
    bf16x8 a1 = *(const bf16x8*)(ar + 16 * astride + ks * 32);
#pragma unroll
    for (int i = 0; i < NTW; ++i) {
      acc[0][i] = __builtin_amdgcn_mfma_f32_16x16x32_bf16(a0, bcur[i], acc[0][i], 0, 0, 0);
      acc[1][i] = __builtin_amdgcn_mfma_f32_16x16x32_bf16(a1, bcur[i], acc[1][i], 0, 0, 0);
    }
    if (ks + 1 < KSTEPS) {
#pragma unroll
      for (int i = 0; i < NTW; ++i) bcur[i] = bnxt[i];
    }
  }
}

// bias + relu + LayerNorm over W = 8*NTW*16 cols, 32 rows (2 mtiles).
// red layout [wave][32 rows] float2: conflict-free writes, broadcast reads (r1-proven).
template<int W, int NTW>
__device__ __forceinline__ void epilogue_ln2(f32x4 acc[2][NTW],
    const float* __restrict__ bias, const float* __restrict__ g, const float* __restrict__ bb,
    int nt0, __bf16* Adst, int dstride, int dstcol0,
    float2* red, int wave, int lane)
{
  const int quad = lane >> 4, ln = lane & 15;
  float x[2][NTW][4];
#pragma unroll
  for (int i = 0; i < NTW; ++i) {
    int n = (nt0 + i) * 16 + ln;
    float b = bias[n];
#pragma unroll
    for (int mt = 0; mt < 2; ++mt)
#pragma unroll
      for (int r = 0; r < 4; ++r)
        x[mt][i][r] = fmaxf(acc[mt][i][r] + b, 0.f);
  }
#pragma unroll
  for (int mt = 0; mt < 2; ++mt) {
    float s[4] = {0, 0, 0, 0}, q[4] = {0, 0, 0, 0};
#pragma unroll
    for (int i = 0; i < NTW; ++i)
#pragma unroll
      for (int r = 0; r < 4; ++r) { s[r] += x[mt][i][r]; q[r] += x[mt][i][r] * x[mt][i][r]; }
#pragma unroll
    for (int m2 = 1; m2 < 16; m2 <<= 1)
#pragma unroll
      for (int r = 0; r < 4; ++r) {
        s[r] += __shfl_xor(s[r], m2, 64);
        q[r] += __shfl_xor(q[r], m2, 64);
      }
    if (ln == 0) {
#pragma unroll
      for (int r = 0; r < 4; ++r)
        red[wave * 32 + mt * 16 + quad * 4 + r] = make_float2(s[r], q[r]);
    }
  }
  __syncthreads();
#pragma unroll
  for (int mt = 0; mt < 2; ++mt)
#pragma unroll
    for (int r = 0; r < 4; ++r) {
      int m = mt * 16 + quad * 4 + r;
      float tot = 0.f, totq = 0.f;
#pragma unroll
      for (int w2 = 0; w2 < 8; ++w2) {
        float2 t = red[w2 * 32 + m];
        tot += t.x; totq += t.y;
      }
      float mu = tot / (float)W;
      float var = totq / (float)W - mu * mu;
      float rs = rsqrtf(var + 1e-5f);
#pragma unroll
      for (int i = 0; i < NTW; ++i) {
        int n = (nt0 + i) * 16 + ln;
        float o = (x[mt][i][r] - mu) * rs * g[n] + bb[n];
        Adst[m * dstride + dstcol0 + n] = (__bf16)o;
      }
    }
  __syncthreads();
}

__global__ __launch_bounds__(512, 8) void critic_kernel(
    const float* __restrict__ obs, const float* __restrict__ pref,
    const float* __restrict__ h_b1, const float* __restrict__ h_g1, const float* __restrict__ h_bb1,
    const float* __restrict__ h_b2, const float* __restrict__ h_g2, const float* __restrict__ h_bb2,
    const float* __restrict__ p_w, const float* __restrict__ p_b,
    const float* __restrict__ p_g, const float* __restrict__ p_bb,
    const float* __restrict__ s_b1, const float* __restrict__ s_g1, const float* __restrict__ s_bb1,
    const float* __restrict__ s_b2, const float* __restrict__ s_g2, const float* __restrict__ s_bb2,
    const float* __restrict__ qd_b, const float* __restrict__ qe_b,
    const __bf16* __restrict__ wsb, float* __restrict__ out)
{
  // 32 rows/block, 8 waves, LDS ~34.3 KB -> 4 blocks/CU (r1 occupancy skeleton kept).
  // obs cols [0,448) are NOT staged: s1 reads them direct-from-global (identical
  // addresses across all 8 waves -> L1 broadcast). Halves B L2-stream per row.
  __shared__ __align__(16) __bf16 A_s[32 * 264];   // 16896 B
  __shared__ __align__(16) __bf16 A2[32 * 200];    // 12800 B: s1 k[448,640): h2->0-127, p->128-191
  __shared__ __align__(16) __bf16 A_h[32 * 40];    //  2560 B
  __shared__ __align__(16) float2 red[8 * 32];     //  2048 B

  const int tid = threadIdx.x;
  const int wave = tid >> 6, lane = tid & 63;
  const int ln = lane & 15, quad = lane >> 4;
  const int rowbase = blockIdx.x * 32;

  // ---------- front-end: each of 8 waves owns 4 rows (hist + p only) ----------
  float pw0 = p_w[lane], pw1 = p_w[64 + lane], pb = p_b[lane];
  float pg = p_g[lane], pbb = p_bb[lane];
#pragma unroll
  for (int r = 0; r < 4; ++r) {
    int row = wave * 4 + r;
    int grow = rowbase + row;
    const float* orow = obs + (size_t)grow * 512;
    // histogram of cols [68,132) via ballot
    float w = orow[68 + lane];
    int bi = (int)floorf(w);
    bi = bi < 0 ? 0 : (bi > 9 ? 9 : bi);
    bool valid = (w >= 0.f) && (w <= 10.f);
    float tot = 0.f, mine = 0.f;
#pragma unroll
    for (int b = 0; b < 10; ++b) {
      unsigned long long mk = __ballot(valid && (bi == b));
      float c = (float)__popcll(mk);
      tot += c;
      if (lane == b) mine = c;
    }
    float inv = 1.f / (tot + 1e-8f);
    if (lane < 32) A_h[row * 40 + lane] = (__bf16)((lane < 10) ? mine * inv : 0.f);
    // p layer: 2 -> 64, relu, LN over 64 lanes -> A2 cols [128,192)
    float a0 = pref[grow * 2], a1 = pref[grow * 2 + 1];
    float v = fmaxf(fmaf(a0, pw0, fmaf(a1, pw1, pb)), 0.f);
    float s1v = v, s2v = v * v;
#pragma unroll
    for (int m2 = 1; m2 < 64; m2 <<= 1) {
      s1v += __shfl_xor(s1v, m2, 64);
      s2v += __shfl_xor(s2v, m2, 64);
    }
    float mu = s1v * (1.f / 64.f);
    float var = s2v * (1.f / 64.f) - mu * mu;
    float o = (v - mu) * rsqrtf(var + 1e-5f) * pg + pbb;
    A2[row * 200 + 128 + lane] = (__bf16)o;
  }
  __syncthreads();

  // ---------- h1: (32x32)@(32x128) ----------
  {
    f32x4 acc[2][1] = {};
    run_gemm2<1, 8, 1>(A_h, 40, (const bf16x8*)(wsb + OFF_WH1), wave, lane, acc);
    epilogue_ln2<128, 1>(acc, h_b1, h_g1, h_bb1, wave, A_s, 264, 0, red, wave, lane);
  }
  // ---------- h2: (32x128)@(128x128) -> A2 cols [0,128) ----------
  {
    f32x4 acc[2][1] = {};
    run_gemm2<4, 8, 1>(A_s, 264, (const bf16x8*)(wsb + OFF_WH2), wave, lane, acc);
    epilogue_ln2<128, 1>(acc, h_b2, h_g2, h_bb2, wave, A2, 200, 0, red, wave, lane);
  }
  // ---------- s1: (32x640)@(640x256); k<448 direct from obs, k>=448 from A2 ----------
  {
    f32x4 acc[2][2] = {};
    const bf16x8* B1 = (const bf16x8*)(wsb + OFF_W1);
    const int nt0 = wave * 2;
    bf16x8 bcur[2];
    bcur[0] = B1[nt0 * 64 + lane];
    bcur[1] = B1[(nt0 + 1) * 64 + lane];
    // per-lane A row bases (fp32 global), quad folded in: +quad*8 floats
    const float* ga0 = obs + (size_t)(rowbase + ln) * 512 + quad * 8;
    const float* ga1 = ga0 + 16 * 512;
    const __bf16* la = A2 + ln * 200 + quad * 8;
#pragma unroll
    for (int ks = 0; ks < 20; ++ks) {
      bf16x8 bnxt[2];
      if (ks + 1 < 20) {
        bnxt[0] = B1[((ks + 1) * 16 + nt0) * 64 + lane];
        bnxt[1] = B1[((ks + 1) * 16 + nt0 + 1) * 64 + lane];
      }
      bf16x8 a0, a1;
      if (ks < 14) {
        // combined col c = ks*32+quad*8+j ; obs col = c<68 ? c : c+64.
        // float4 groups never straddle the cut (68 % 4 == 0).
        int o1, o2;   // float offsets from ga base
        if (ks < 2)        { o1 = ks * 32;              o2 = o1 + 4; }
        else if (ks == 2)  { o1 = (quad == 0) ? 64 : 128; o2 = 132; }
        else               { o1 = ks * 32 + 64;         o2 = o1 + 4; }
        float4 v00 = *(const float4*)(ga0 + o1);
        float4 v01 = *(const float4*)(ga0 + o2);
        float4 v10 = *(const float4*)(ga1 + o1);
        float4 v11 = *(const float4*)(ga1 + o2);
        a0[0] = (__bf16)v00.x; a0[1] = (__bf16)v00.y; a0[2] = (__bf16)v00.z; a0[3] = (__bf16)v00.w;
        a0[4] = (__bf16)v01.x; a0[5] = (__bf16)v01.y; a0[6] = (__bf16)v01.z; a0[7] = (__bf16)v01.w;
        a1[0] = (__bf16)v10.x; a1[1] = (__bf16)v10.y; a1[2] = (__bf16)v10.z; a1[3] = (__bf16)v10.w;
        a1[4] = (__bf16)v11.x; a1[5] = (__bf16)v11.y; a1[6] = (__bf16)v11.z; a1[7] = (__bf16)v11.w;
      } else {
        a0 = *(const bf16x8*)(la + (ks - 14) * 32);
        a1 = *(const bf16x8*)(la + 16 * 200 + (ks - 14) * 32);
      }
      acc[0][0] = __builtin_amdgcn_mfma_f32_16x16x32_bf16(a0, bcur[0], acc[0][0], 0, 0, 0);
      acc[1][0] = __builtin_amdgcn_mfma_f32_16x16x32_bf16(a1, bcur[0], acc[1][0], 0, 0, 0);
      acc[0][1] = __builtin_amdgcn_mfma_f32_16x16x32_bf16(a0, bcur[1], acc[0][1], 0, 0, 0);
      acc[1][1] = __builtin_amdgcn_mfma_f32_16x16x32_bf16(a1, bcur[1], acc[1][1], 0, 0, 0);
      if (ks + 1 < 20) { bcur[0] = bnxt[0]; bcur[1] = bnxt[1]; }
    }
    epilogue_ln2<256, 2>(acc, s_b1, s_g1, s_bb1, nt0, A_s, 264, 0, red, wave, lane);
  }
  // ---------- s2: (32x256)@(256x256), in-place (epilogue barrier protects) ----------
  {
    f32x4 acc[2][2] = {};
    run_gemm2<8, 16, 2>(A_s, 264, (const bf16x8*)(wsb + OFF_W2), wave * 2, lane, acc);
    epilogue_ln2<256, 2>(acc, s_b2, s_g2, s_bb2, wave * 2, A_s, 264, 0, red, wave, lane);
  }
  // ---------- q: (32x256)@(256x128), bias, direct fp32 store ----------
  {
    f32x4 acc[2][1] = {};
    run_gemm2<8, 8, 1>(A_s, 264, (const bf16x8*)(wsb + OFF_WQ), wave, lane, acc);
    int n = wave * 16 + ln;
    float qb = (n & 1) ? qe_b[n >> 1] : qd_b[n >> 1];
#pragma unroll
    for (int mt = 0; mt < 2; ++mt)
#pragma unroll
      for (int r = 0; r < 4; ++r) {
        int m = mt * 16 + quad * 4 + r;
        out[(size_t)(rowbase + m) * 128 + n] = acc[mt][0][r] + qb;
      }
  }
}

extern "C" void kernel_launch(void* const* d_in, const int* in_sizes, int n_in,
                              void* d_out, int out_size, void* d_ws, size_t ws_size,
                              hipStream_t stream) {
  const float* obs    = (const float*)d_in[0];
  const float* pref   = (const float*)d_in[1];
  const float* h_w1   = (const float*)d_in[2];
  const float* h_b1   = (const float*)d_in[3];
  const float* h_g1   = (const float*)d_in[4];
  const float* h_bb1  = (const float*)d_in[5];
  const float* h_w2   = (const float*)d_in[6];
  const float* h_b2   = (const float*)d_in[7];
  const float* h_g2   = (const float*)d_in[8];
  const float* h_bb2  = (const float*)d_in[9];
  const float* p_w    = (const float*)d_in[10];
  const float* p_b    = (const float*)d_in[11];
  const float* p_g    = (const float*)d_in[12];
  const float* p_bb   = (const float*)d_in[13];
  const float* s_w1   = (const float*)d_in[14];
  const float* s_b1   = (const float*)d_in[15];
  const float* s_g1   = (const float*)d_in[16];
  const float* s_bb1  = (const float*)d_in[17];
  const float* s_w2   = (const float*)d_in[18];
  const float* s_b2   = (const float*)d_in[19];
  const float* s_g2   = (const float*)d_in[20];
  const float* s_bb2  = (const float*)d_in[21];
  const float* qd_w   = (const float*)d_in[22];
  const float* qd_b   = (const float*)d_in[23];
  const float* qe_w   = (const float*)d_in[24];
  const float* qe_b   = (const float*)d_in[25];

  __bf16* wsb = (__bf16*)d_ws;
  int B = in_sizes[0] / 512;
  int nblocks = B / 32;

  prep_kernel<<<(WS_ELEMS + 255) / 256, 256, 0, stream>>>(s_w1, s_w2, qd_w, qe_w, h_w1, h_w2, wsb);
  critic_kernel<<<nblocks, 512, 0, stream>>>(
      obs, pref, h_b1, h_g1, h_bb1, h_b2, h_g2, h_bb2,
      p_w, p_b, p_g, p_bb, s_b1, s_g1, s_bb1, s_b2, s_g2, s_bb2,
      qd_b, qe_b, (const __bf16*)wsb, (float*)d_out);
}

// Round 6
// 350.500 us; speedup vs baseline: 1.1300x; 1.1300x over previous
//
#include <hip/hip_runtime.h>

typedef __bf16 bf16x8 __attribute__((ext_vector_type(8)));
typedef __bf16 bf16x4 __attribute__((ext_vector_type(4)));
typedef float  f32x4  __attribute__((ext_vector_type(4)));

// ws layout (bf16 elements), all in MFMA b-fragment order [kstep][ntile][lane][8]
#define OFF_W1  0        // 20 ksteps * 16 nt * 512  = 163840   (s_w1 640x256)
#define OFF_W2  163840   //  8 * 16 * 512            =  65536   (s_w2 256x256)
#define OFF_WQ  229376   //  8 *  8 * 512            =  32768   (qd|qe interleaved 256x128)
#define OFF_WH1 262144   //  1 *  8 * 512            =   4096   (h_w1 10->32 zero-pad x128)
#define OFF_WH2 266240   //  4 *  8 * 512            =  16384   (h_w2 128x128)
#define WS_ELEMS 282624

__global__ __launch_bounds__(256) void prep_kernel(
    const float* __restrict__ s_w1, const float* __restrict__ s_w2,
    const float* __restrict__ qd_w, const float* __restrict__ qe_w,
    const float* __restrict__ h_w1, const float* __restrict__ h_w2,
    __bf16* __restrict__ wsb)
{
  int idx = blockIdx.x * 256 + threadIdx.x;
  if (idx >= WS_ELEMS) return;
  float val = 0.f;
  if (idx < OFF_W2) {                       // W1: K=640, N=256
    int t = idx;
    int j = t & 7, l = (t >> 3) & 63, rest = t >> 9;
    int nt = rest & 15, ks = rest >> 4;
    int k = ks * 32 + (l >> 4) * 8 + j, n = nt * 16 + (l & 15);
    val = s_w1[k * 256 + n];
  } else if (idx < OFF_WQ) {                // W2: K=256, N=256
    int t = idx - OFF_W2;
    int j = t & 7, l = (t >> 3) & 63, rest = t >> 9;
    int nt = rest & 15, ks = rest >> 4;
    int k = ks * 32 + (l >> 4) * 8 + j, n = nt * 16 + (l & 15);
    val = s_w2[k * 256 + n];
  } else if (idx < OFF_WH1) {               // Wq: K=256, N=128, n = 2a+sel
    int t = idx - OFF_WQ;
    int j = t & 7, l = (t >> 3) & 63, rest = t >> 9;
    int nt = rest & 7, ks = rest >> 3;
    int k = ks * 32 + (l >> 4) * 8 + j, n = nt * 16 + (l & 15);
    int a = n >> 1;
    val = (n & 1) ? qe_w[k * 64 + a] : qd_w[k * 64 + a];
  } else if (idx < OFF_WH2) {               // Wh1: K=10 padded to 32, N=128
    int t = idx - OFF_WH1;
    int j = t & 7, l = (t >> 3) & 63, rest = t >> 9;
    int nt = rest & 7;
    int k = (l >> 4) * 8 + j, n = nt * 16 + (l & 15);
    val = (k < 10) ? h_w1[k * 128 + n] : 0.f;
  } else {                                  // Wh2: K=128, N=128
    int t = idx - OFF_WH2;
    int j = t & 7, l = (t >> 3) & 63, rest = t >> 9;
    int nt = rest & 7, ks = rest >> 3;
    int k = ks * 32 + (l >> 4) * 8 + j, n = nt * 16 + (l & 15);
    val = h_w2[k * 128 + n];
  }
  wsb[idx] = (__bf16)val;
}

// DPP rotate-add: VALU-pipe lane exchange (~4cyc dep latency) replacing
// __shfl_xor's ds_bpermute (~60cyc, LDS pipe, contended by all 32 waves/CU).
template<int CTRL>
__device__ __forceinline__ float dppadd(float x) {
  int p = __builtin_amdgcn_mov_dpp(__float_as_int(x), CTRL, 0xF, 0xF, true);
  return x + __int_as_float(p);
}
// full sum across each 16-lane row, result in every lane: ror:1,2,4,8 tree
__device__ __forceinline__ float row16_reduce(float x) {
  x = dppadd<0x121>(x);
  x = dppadd<0x122>(x);
  x = dppadd<0x124>(x);
  x = dppadd<0x128>(x);
  return x;
}

// 16 rows (1 mtile), 8 waves split N. A in LDS bf16, B pre-swizzled in global.
template<int KSTEPS, int NT_TOT, int NTW>
__device__ __forceinline__ void run_gemm(const __bf16* A, int astride,
    const bf16x8* __restrict__ Bsw, int wave, int lane, f32x4 acc[NTW])
{
  const int quad = lane >> 4, ln = lane & 15;
  const int ntb = wave * NTW;
  bf16x8 bcur[NTW];
#pragma unroll
  for (int i = 0; i < NTW; ++i) bcur[i] = Bsw[(ntb + i) * 64 + lane];
#pragma unroll
  for (int ks = 0; ks < KSTEPS; ++ks) {
    bf16x8 bnxt[NTW];
    if (ks + 1 < KSTEPS) {
#pragma unroll
      for (int i = 0; i < NTW; ++i)
        bnxt[i] = Bsw[((ks + 1) * NT_TOT + ntb + i) * 64 + lane];
    }
    bf16x8 a = *(const bf16x8*)(A + ln * astride + ks * 32 + quad * 8);
#pragma unroll
    for (int i = 0; i < NTW; ++i)
      acc[i] = __builtin_amdgcn_mfma_f32_16x16x32_bf16(a, bcur[i], acc[i], 0, 0, 0);
    if (ks + 1 < KSTEPS) {
#pragma unroll
      for (int i = 0; i < NTW; ++i) bcur[i] = bnxt[i];
    }
  }
}

// bias + relu + LayerNorm(width W, split across 8 waves) -> bf16 LDS tile.
// Cross-lane reduce via DPP (VALU pipe); cross-wave via red[wave][16] (conflict-free).
template<int W, int NTW>
__device__ __forceinline__ void epilogue_ln(f32x4 acc[NTW],
    const float* __restrict__ bias, const float* __restrict__ g, const float* __restrict__ bb,
    __bf16* Adst, int dstride, int dstcol0,
    float2* red, int wave, int lane)
{
  const int quad = lane >> 4, ln = lane & 15;
  float x[NTW][4];
#pragma unroll
  for (int i = 0; i < NTW; ++i) {
    int n = (wave * NTW + i) * 16 + ln;
    float b = bias[n];
#pragma unroll
    for (int r = 0; r < 4; ++r)
      x[i][r] = fmaxf(acc[i][r] + b, 0.f);
  }
  float s[4] = {0, 0, 0, 0}, q[4] = {0, 0, 0, 0};
#pragma unroll
  for (int i = 0; i < NTW; ++i)
#pragma unroll
    for (int r = 0; r < 4; ++r) { s[r] += x[i][r]; q[r] += x[i][r] * x[i][r]; }
#pragma unroll
  for (int r = 0; r < 4; ++r) {
    s[r] = row16_reduce(s[r]);
    q[r] = row16_reduce(q[r]);
  }
  if (ln == 0) {
#pragma unroll
    for (int r = 0; r < 4; ++r)
      red[wave * 16 + quad * 4 + r] = make_float2(s[r], q[r]);
  }
  __syncthreads();
#pragma unroll
  for (int r = 0; r < 4; ++r) {
    int m = quad * 4 + r;
    float tot = 0.f, totq = 0.f;
#pragma unroll
    for (int w2 = 0; w2 < 8; ++w2) {
      float2 t = red[w2 * 16 + m];
      tot += t.x; totq += t.y;
    }
    float mu = tot / (float)W;
    float var = totq / (float)W - mu * mu;
    float rs = rsqrtf(var + 1e-5f);
#pragma unroll
    for (int i = 0; i < NTW; ++i) {
      int n = (wave * NTW + i) * 16 + ln;
      float o = (x[i][r] - mu) * rs * g[n] + bb[n];
      Adst[m * dstride + dstcol0 + n] = (__bf16)o;
    }
  }
  __syncthreads();
}

__global__ __launch_bounds__(512, 8) void critic_kernel(
    const float* __restrict__ obs, const float* __restrict__ pref,
    const float* __restrict__ h_b1, const float* __restrict__ h_g1, const float* __restrict__ h_bb1,
    const float* __restrict__ h_b2, const float* __restrict__ h_g2, const float* __restrict__ h_bb2,
    const float* __restrict__ p_w, const float* __restrict__ p_b,
    const float* __restrict__ p_g, const float* __restrict__ p_bb,
    const float* __restrict__ s_b1, const float* __restrict__ s_g1, const float* __restrict__ s_bb1,
    const float* __restrict__ s_b2, const float* __restrict__ s_g2, const float* __restrict__ s_bb2,
    const float* __restrict__ qd_b, const float* __restrict__ qe_b,
    const __bf16* __restrict__ wsb, float* __restrict__ out)
{
  // 16 rows/block, 8 waves, LDS ~31.5 KB -> 4 blocks/CU (r1-proven best skeleton).
  __shared__ __align__(16) __bf16 A_comb[16 * 648];  // 20736 B
  __shared__ __align__(16) __bf16 A_s[16 * 264];     //  8448 B
  __shared__ __align__(16) __bf16 A_h[16 * 40];      //  1280 B
  __shared__ float2 red[128];                        //  1024 B

  const int tid = threadIdx.x;
  const int wave = tid >> 6, lane = tid & 63;
  const int rowbase = blockIdx.x * 16;

  // ---------- front-end: each of 8 waves owns 2 rows ----------
  float pw0 = p_w[lane], pw1 = p_w[64 + lane], pb = p_b[lane];
  float pg = p_g[lane], pbb = p_bb[lane];
#pragma unroll
  for (int r = 0; r < 2; ++r) {
    int row = wave * 2 + r;
    int grow = rowbase + row;
    const float* orow = obs + (size_t)grow * 512;
    // obs_wo -> combined cols [0,448): excision at col 68 is float4-aligned.
#pragma unroll
    for (int j = 0; j < 2; ++j) {
      int l = lane + 64 * j;
      if (l < 112) {
        int src4 = (l < 17) ? l : l + 16;   // skip obs cols [68,132)
        float4 v = *(const float4*)(orow + 4 * src4);
        bf16x4 o;
        o[0] = (__bf16)v.x; o[1] = (__bf16)v.y; o[2] = (__bf16)v.z; o[3] = (__bf16)v.w;
        *(bf16x4*)(&A_comb[row * 648 + 4 * l]) = o;
      }
    }
    // histogram of cols [68,132) via ballot
    float w = orow[68 + lane];
    int bi = (int)floorf(w);
    bi = bi < 0 ? 0 : (bi > 9 ? 9 : bi);
    bool valid = (w >= 0.f) && (w <= 10.f);
    float tot = 0.f, mine = 0.f;
#pragma unroll
    for (int b = 0; b < 10; ++b) {
      unsigned long long mk = __ballot(valid && (bi == b));
      float c = (float)__popcll(mk);
      tot += c;
      if (lane == b) mine = c;
    }
    float inv = 1.f / (tot + 1e-8f);
    if (lane < 32) A_h[row * 40 + lane] = (__bf16)((lane < 10) ? mine * inv : 0.f);
    // p layer: 2 -> 64, relu, LN over 64 lanes -> combined cols [576,640)
    float a0 = pref[grow * 2], a1 = pref[grow * 2 + 1];
    float v = fmaxf(fmaf(a0, pw0, fmaf(a1, pw1, pb)), 0.f);
    float s1 = v, s2 = v * v;
    s1 = row16_reduce(s1); s2 = row16_reduce(s2);
    s1 += __shfl_xor(s1, 16, 64); s2 += __shfl_xor(s2, 16, 64);
    s1 += __shfl_xor(s1, 32, 64); s2 += __shfl_xor(s2, 32, 64);
    float mu = s1 * (1.f / 64.f);
    float var = s2 * (1.f / 64.f) - mu * mu;
    float o = (v - mu) * rsqrtf(var + 1e-5f) * pg + pbb;
    A_comb[row * 648 + 576 + lane] = (__bf16)o;
  }
  __syncthreads();

  // ---------- h1: (16x32)@(32x128) ----------
  {
    f32x4 acc[1] = {};
    run_gemm<1, 8, 1>(A_h, 40, (const bf16x8*)(wsb + OFF_WH1), wave, lane, acc);
    epilogue_ln<128, 1>(acc, h_b1, h_g1, h_bb1, A_s, 264, 0, red, wave, lane);
  }
  // ---------- h2: (16x128)@(128x128) -> combined cols [448,576) ----------
  {
    f32x4 acc[1] = {};
    run_gemm<4, 8, 1>(A_s, 264, (const bf16x8*)(wsb + OFF_WH2), wave, lane, acc);
    epilogue_ln<128, 1>(acc, h_b2, h_g2, h_bb2, A_comb, 648, 448, red, wave, lane);
  }
  // ---------- s1: (16x640)@(640x256) ----------
  {
    f32x4 acc[2] = {};
    run_gemm<20, 16, 2>(A_comb, 648, (const bf16x8*)(wsb + OFF_W1), wave, lane, acc);
    epilogue_ln<256, 2>(acc, s_b1, s_g1, s_bb1, A_s, 264, 0, red, wave, lane);
  }
  // ---------- s2: (16x256)@(256x256), in-place (epilogue barrier protects) ----------
  {
    f32x4 acc[2] = {};
    run_gemm<8, 16, 2>(A_s, 264, (const bf16x8*)(wsb + OFF_W2), wave, lane, acc);
    epilogue_ln<256, 2>(acc, s_b2, s_g2, s_bb2, A_s, 264, 0, red, wave, lane);
  }
  // ---------- q: (16x256)@(256x128), bias, direct fp32 store ----------
  {
    f32x4 acc[1] = {};
    run_gemm<8, 8, 1>(A_s, 264, (const bf16x8*)(wsb + OFF_WQ), wave, lane, acc);
    const int quad = lane >> 4, ln = lane & 15;
    int n = wave * 16 + ln;
    float qb = (n & 1) ? qe_b[n >> 1] : qd_b[n >> 1];
#pragma unroll
    for (int r = 0; r < 4; ++r) {
      int m = quad * 4 + r;
      out[(size_t)(rowbase + m) * 128 + n] = acc[0][r] + qb;
    }
  }
}

extern "C" void kernel_launch(void* const* d_in, const int* in_sizes, int n_in,
                              void* d_out, int out_size, void* d_ws, size_t ws_size,
                              hipStream_t stream) {
  const float* obs    = (const float*)d_in[0];
  const float* pref   = (const float*)d_in[1];
  const float* h_w1   = (const float*)d_in[2];
  const float* h_b1   = (const float*)d_in[3];
  const float* h_g1   = (const float*)d_in[4];
  const float* h_bb1  = (const float*)d_in[5];
  const float* h_w2   = (const float*)d_in[6];
  const float* h_b2   = (const float*)d_in[7];
  const float* h_g2   = (const float*)d_in[8];
  const float* h_bb2  = (const float*)d_in[9];
  const float* p_w    = (const float*)d_in[10];
  const float* p_b    = (const float*)d_in[11];
  const float* p_g    = (const float*)d_in[12];
  const float* p_bb   = (const float*)d_in[13];
  const float* s_w1   = (const float*)d_in[14];
  const float* s_b1   = (const float*)d_in[15];
  const float* s_g1   = (const float*)d_in[16];
  const float* s_bb1  = (const float*)d_in[17];
  const float* s_w2   = (const float*)d_in[18];
  const float* s_b2   = (const float*)d_in[19];
  const float* s_g2   = (const float*)d_in[20];
  const float* s_bb2  = (const float*)d_in[21];
  const float* qd_w   = (const float*)d_in[22];
  const float* qd_b   = (const float*)d_in[23];
  const float* qe_w   = (const float*)d_in[24];
  const float* qe_b   = (const float*)d_in[25];

  __bf16* wsb = (__bf16*)d_ws;
  int B = in_sizes[0] / 512;
  int nblocks = B / 16;

  prep_kernel<<<(WS_ELEMS + 255) / 256, 256, 0, stream>>>(s_w1, s_w2, qd_w, qe_w, h_w1, h_w2, wsb);
  critic_kernel<<<nblocks, 512, 0, stream>>>(
      obs, pref, h_b1, h_g1, h_bb1, h_b2, h_g2, h_bb2,
      p_w, p_b, p_g, p_bb, s_b1, s_g1, s_bb1, s_b2, s_g2, s_bb2,
      qd_b, qe_b, (const __bf16*)wsb, (float*)d_out);
}

// Round 7
// 336.591 us; speedup vs baseline: 1.1767x; 1.0413x over previous
//
#include <hip/hip_runtime.h>

typedef __bf16 bf16x8 __attribute__((ext_vector_type(8)));
typedef __bf16 bf16x4 __attribute__((ext_vector_type(4)));
typedef float  f32x4  __attribute__((ext_vector_type(4)));

// ws layout (bf16 elements), all in MFMA b-fragment order [kstep][ntile][lane][8]
#define OFF_W1  0        // 20 ksteps * 16 nt * 512  = 163840   (s_w1 640x256)
#define OFF_W2  163840   //  8 * 16 * 512            =  65536   (s_w2 256x256)
#define OFF_WQ  229376   //  8 *  8 * 512            =  32768   (qd|qe interleaved 256x128)
#define OFF_WH1 262144   //  1 *  8 * 512            =   4096   (h_w1 10->32 zero-pad x128)
#define OFF_WH2 266240   //  4 *  8 * 512            =  16384   (h_w2 128x128)
#define WS_ELEMS 282624

__global__ __launch_bounds__(256) void prep_kernel(
    const float* __restrict__ s_w1, const float* __restrict__ s_w2,
    const float* __restrict__ qd_w, const float* __restrict__ qe_w,
    const float* __restrict__ h_w1, const float* __restrict__ h_w2,
    __bf16* __restrict__ wsb)
{
  int idx = blockIdx.x * 256 + threadIdx.x;
  if (idx >= WS_ELEMS) return;
  float val = 0.f;
  if (idx < OFF_W2) {                       // W1: K=640, N=256
    int t = idx;
    int j = t & 7, l = (t >> 3) & 63, rest = t >> 9;
    int nt = rest & 15, ks = rest >> 4;
    int k = ks * 32 + (l >> 4) * 8 + j, n = nt * 16 + (l & 15);
    val = s_w1[k * 256 + n];
  } else if (idx < OFF_WQ) {                // W2: K=256, N=256
    int t = idx - OFF_W2;
    int j = t & 7, l = (t >> 3) & 63, rest = t >> 9;
    int nt = rest & 15, ks = rest >> 4;
    int k = ks * 32 + (l >> 4) * 8 + j, n = nt * 16 + (l & 15);
    val = s_w2[k * 256 + n];
  } else if (idx < OFF_WH1) {               // Wq: K=256, N=128, n = 2a+sel
    int t = idx - OFF_WQ;
    int j = t & 7, l = (t >> 3) & 63, rest = t >> 9;
    int nt = rest & 7, ks = rest >> 3;
    int k = ks * 32 + (l >> 4) * 8 + j, n = nt * 16 + (l & 15);
    int a = n >> 1;
    val = (n & 1) ? qe_w[k * 64 + a] : qd_w[k * 64 + a];
  } else if (idx < OFF_WH2) {               // Wh1: K=10 padded to 32, N=128
    int t = idx - OFF_WH1;
    int j = t & 7, l = (t >> 3) & 63, rest = t >> 9;
    int nt = rest & 7;
    int k = (l >> 4) * 8 + j, n = nt * 16 + (l & 15);
    val = (k < 10) ? h_w1[k * 128 + n] : 0.f;
  } else {                                  // Wh2: K=128, N=128
    int t = idx - OFF_WH2;
    int j = t & 7, l = (t >> 3) & 63, rest = t >> 9;
    int nt = rest & 7, ks = rest >> 3;
    int k = ks * 32 + (l >> 4) * 8 + j, n = nt * 16 + (l & 15);
    val = h_w2[k * 128 + n];
  }
  wsb[idx] = (__bf16)val;
}

// DPP rotate-add: VALU-pipe lane exchange (~4cyc dep latency) replacing
// __shfl_xor's ds_bpermute (~60cyc, LDS pipe, contended by all 32 waves/CU).
template<int CTRL>
__device__ __forceinline__ float dppadd(float x) {
  int p = __builtin_amdgcn_mov_dpp(__float_as_int(x), CTRL, 0xF, 0xF, true);
  return x + __int_as_float(p);
}
// full sum across each 16-lane row, result in every lane: ror:1,2,4,8 tree
__device__ __forceinline__ float row16_reduce(float x) {
  x = dppadd<0x121>(x);
  x = dppadd<0x122>(x);
  x = dppadd<0x124>(x);
  x = dppadd<0x128>(x);
  return x;
}

// 16 rows (1 mtile), 8 waves split N. A in LDS bf16, B pre-swizzled in global.
template<int KSTEPS, int NT_TOT, int NTW>
__device__ __forceinline__ void run_gemm(const __bf16* A, int astride,
    const bf16x8* __restrict__ Bsw, int wave, int lane, f32x4 acc[NTW])
{
  const int quad = lane >> 4, ln = lane & 15;
  const int ntb = wave * NTW;
  bf16x8 bcur[NTW];
#pragma unroll
  for (int i = 0; i < NTW; ++i) bcur[i] = Bsw[(ntb + i) * 64 + lane];
#pragma unroll
  for (int ks = 0; ks < KSTEPS; ++ks) {
    bf16x8 bnxt[NTW];
    if (ks + 1 < KSTEPS) {
#pragma unroll
      for (int i = 0; i < NTW; ++i)
        bnxt[i] = Bsw[((ks + 1) * NT_TOT + ntb + i) * 64 + lane];
    }
    bf16x8 a = *(const bf16x8*)(A + ln * astride + ks * 32 + quad * 8);
#pragma unroll
    for (int i = 0; i < NTW; ++i)
      acc[i] = __builtin_amdgcn_mfma_f32_16x16x32_bf16(a, bcur[i], acc[i], 0, 0, 0);
    if (ks + 1 < KSTEPS) {
#pragma unroll
      for (int i = 0; i < NTW; ++i) bcur[i] = bnxt[i];
    }
  }
}

// bias + relu + LayerNorm(width W, split across 8 waves) -> bf16 LDS tile.
// Cross-lane reduce via DPP (VALU pipe). Cross-wave via LDS float atomics into
// red[32] = {s,q} x 16 rows: 8-way same-address serialization handled by LDS HW
// in parallel across 32 addresses. Readback is 2 broadcast ds_read_b128/thread
// (banks {0,8,16,24} per quad) — replaces r6's 32 ds_read_b64 + 64 dep adds.
// red_other is the ping-pong partner, zeroed here (pre-barrier) for the NEXT layer.
template<int W, int NTW>
__device__ __forceinline__ void epilogue_ln(f32x4 acc[NTW],
    const float* __restrict__ bias, const float* __restrict__ g, const float* __restrict__ bb,
    __bf16* Adst, int dstride, int dstcol0,
    float* red, float* red_other, int wave, int lane, int tid)
{
  const int quad = lane >> 4, ln = lane & 15;
  float x[NTW][4];
#pragma unroll
  for (int i = 0; i < NTW; ++i) {
    int n = (wave * NTW + i) * 16 + ln;
    float b = bias[n];
#pragma unroll
    for (int r = 0; r < 4; ++r)
      x[i][r] = fmaxf(acc[i][r] + b, 0.f);
  }
  float s[4] = {0, 0, 0, 0}, q[4] = {0, 0, 0, 0};
#pragma unroll
  for (int i = 0; i < NTW; ++i)
#pragma unroll
    for (int r = 0; r < 4; ++r) { s[r] += x[i][r]; q[r] += x[i][r] * x[i][r]; }
#pragma unroll
  for (int r = 0; r < 4; ++r) {
    s[r] = row16_reduce(s[r]);
    q[r] = row16_reduce(q[r]);
  }
  if (ln == 0) {
#pragma unroll
    for (int r = 0; r < 4; ++r) {
      int m = quad * 4 + r;
      atomicAdd(&red[2 * m], s[r]);
      atomicAdd(&red[2 * m + 1], q[r]);
    }
  }
  if (tid < 32) red_other[tid] = 0.f;   // ping-pong zero for next layer (buffer idle now)
  __syncthreads();
  // totals for this thread's 4 rows: red[2m],red[2m+1], m = quad*4+r
  f32x4 v0 = *(const f32x4*)(red + quad * 8);
  f32x4 v1 = *(const f32x4*)(red + quad * 8 + 4);
  float ts[4] = {v0[0], v0[2], v1[0], v1[2]};
  float tq[4] = {v0[1], v0[3], v1[1], v1[3]};
#pragma unroll
  for (int r = 0; r < 4; ++r) {
    int m = quad * 4 + r;
    float mu = ts[r] / (float)W;
    float var = tq[r] / (float)W - mu * mu;
    float rs = rsqrtf(var + 1e-5f);
#pragma unroll
    for (int i = 0; i < NTW; ++i) {
      int n = (wave * NTW + i) * 16 + ln;
      float o = (x[i][r] - mu) * rs * g[n] + bb[n];
      Adst[m * dstride + dstcol0 + n] = (__bf16)o;
    }
  }
  __syncthreads();
}

__global__ __launch_bounds__(512, 8) void critic_kernel(
    const float* __restrict__ obs, const float* __restrict__ pref,
    const float* __restrict__ h_b1, const float* __restrict__ h_g1, const float* __restrict__ h_bb1,
    const float* __restrict__ h_b2, const float* __restrict__ h_g2, const float* __restrict__ h_bb2,
    const float* __restrict__ p_w, const float* __restrict__ p_b,
    const float* __restrict__ p_g, const float* __restrict__ p_bb,
    const float* __restrict__ s_b1, const float* __restrict__ s_g1, const float* __restrict__ s_bb1,
    const float* __restrict__ s_b2, const float* __restrict__ s_g2, const float* __restrict__ s_bb2,
    const float* __restrict__ qd_b, const float* __restrict__ qe_b,
    const __bf16* __restrict__ wsb, float* __restrict__ out)
{
  // 16 rows/block, 8 waves, LDS ~30.7 KB -> 4 blocks/CU (r1-proven best skeleton).
  __shared__ __align__(16) __bf16 A_comb[16 * 648];  // 20736 B
  __shared__ __align__(16) __bf16 A_s[16 * 264];     //  8448 B
  __shared__ __align__(16) __bf16 A_h[16 * 40];      //  1280 B
  __shared__ __align__(16) float redbuf[2][32];      //   256 B (ping-pong LN accumulators)

  const int tid = threadIdx.x;
  const int wave = tid >> 6, lane = tid & 63;
  const int rowbase = blockIdx.x * 16;

  if (tid < 64) redbuf[tid >> 5][tid & 31] = 0.f;

  // ---------- front-end: each of 8 waves owns 2 rows ----------
  float pw0 = p_w[lane], pw1 = p_w[64 + lane], pb = p_b[lane];
  float pg = p_g[lane], pbb = p_bb[lane];
#pragma unroll
  for (int r = 0; r < 2; ++r) {
    int row = wave * 2 + r;
    int grow = rowbase + row;
    const float* orow = obs + (size_t)grow * 512;
    // obs_wo -> combined cols [0,448): excision at col 68 is float4-aligned.
#pragma unroll
    for (int j = 0; j < 2; ++j) {
      int l = lane + 64 * j;
      if (l < 112) {
        int src4 = (l < 17) ? l : l + 16;   // skip obs cols [68,132)
        float4 v = *(const float4*)(orow + 4 * src4);
        bf16x4 o;
        o[0] = (__bf16)v.x; o[1] = (__bf16)v.y; o[2] = (__bf16)v.z; o[3] = (__bf16)v.w;
        *(bf16x4*)(&A_comb[row * 648 + 4 * l]) = o;
      }
    }
    // histogram of cols [68,132) via ballot
    float w = orow[68 + lane];
    int bi = (int)floorf(w);
    bi = bi < 0 ? 0 : (bi > 9 ? 9 : bi);
    bool valid = (w >= 0.f) && (w <= 10.f);
    float tot = 0.f, mine = 0.f;
#pragma unroll
    for (int b = 0; b < 10; ++b) {
      unsigned long long mk = __ballot(valid && (bi == b));
      float c = (float)__popcll(mk);
      tot += c;
      if (lane == b) mine = c;
    }
    float inv = 1.f / (tot + 1e-8f);
    if (lane < 32) A_h[row * 40 + lane] = (__bf16)((lane < 10) ? mine * inv : 0.f);
    // p layer: 2 -> 64, relu, LN over 64 lanes -> combined cols [576,640)
    float a0 = pref[grow * 2], a1 = pref[grow * 2 + 1];
    float v = fmaxf(fmaf(a0, pw0, fmaf(a1, pw1, pb)), 0.f);
    float s1 = v, s2 = v * v;
    s1 = row16_reduce(s1); s2 = row16_reduce(s2);
    s1 += __shfl_xor(s1, 16, 64); s2 += __shfl_xor(s2, 16, 64);
    s1 += __shfl_xor(s1, 32, 64); s2 += __shfl_xor(s2, 32, 64);
    float mu = s1 * (1.f / 64.f);
    float var = s2 * (1.f / 64.f) - mu * mu;
    float o = (v - mu) * rsqrtf(var + 1e-5f) * pg + pbb;
    A_comb[row * 648 + 576 + lane] = (__bf16)o;
  }
  __syncthreads();

  // ---------- h1: (16x32)@(32x128) ----------
  {
    f32x4 acc[1] = {};
    run_gemm<1, 8, 1>(A_h, 40, (const bf16x8*)(wsb + OFF_WH1), wave, lane, acc);
    epilogue_ln<128, 1>(acc, h_b1, h_g1, h_bb1, A_s, 264, 0,
                        redbuf[0], redbuf[1], wave, lane, tid);
  }
  // ---------- h2: (16x128)@(128x128) -> combined cols [448,576) ----------
  {
    f32x4 acc[1] = {};
    run_gemm<4, 8, 1>(A_s, 264, (const bf16x8*)(wsb + OFF_WH2), wave, lane, acc);
    epilogue_ln<128, 1>(acc, h_b2, h_g2, h_bb2, A_comb, 648, 448,
                        redbuf[1], redbuf[0], wave, lane, tid);
  }
  // ---------- s1: (16x640)@(640x256) ----------
  {
    f32x4 acc[2] = {};
    run_gemm<20, 16, 2>(A_comb, 648, (const bf16x8*)(wsb + OFF_W1), wave, lane, acc);
    epilogue_ln<256, 2>(acc, s_b1, s_g1, s_bb1, A_s, 264, 0,
                        redbuf[0], redbuf[1], wave, lane, tid);
  }
  // ---------- s2: (16x256)@(256x256), in-place (epilogue barrier #1 protects) ----------
  {
    f32x4 acc[2] = {};
    run_gemm<8, 16, 2>(A_s, 264, (const bf16x8*)(wsb + OFF_W2), wave, lane, acc);
    epilogue_ln<256, 2>(acc, s_b2, s_g2, s_bb2, A_s, 264, 0,
                        redbuf[1], redbuf[0], wave, lane, tid);
  }
  // ---------- q: (16x256)@(256x128), bias, direct fp32 store ----------
  {
    f32x4 acc[1] = {};
    run_gemm<8, 8, 1>(A_s, 264, (const bf16x8*)(wsb + OFF_WQ), wave, lane, acc);
    const int quad = lane >> 4, ln = lane & 15;
    int n = wave * 16 + ln;
    float qb = (n & 1) ? qe_b[n >> 1] : qd_b[n >> 1];
#pragma unroll
    for (int r = 0; r < 4; ++r) {
      int m = quad * 4 + r;
      out[(size_t)(rowbase + m) * 128 + n] = acc[0][r] + qb;
    }
  }
}

extern "C" void kernel_launch(void* const* d_in, const int* in_sizes, int n_in,
                              void* d_out, int out_size, void* d_ws, size_t ws_size,
                              hipStream_t stream) {
  const float* obs    = (const float*)d_in[0];
  const float* pref   = (const float*)d_in[1];
  const float* h_w1   = (const float*)d_in[2];
  const float* h_b1   = (const float*)d_in[3];
  const float* h_g1   = (const float*)d_in[4];
  const float* h_bb1  = (const float*)d_in[5];
  const float* h_w2   = (const float*)d_in[6];
  const float* h_b2   = (const float*)d_in[7];
  const float* h_g2   = (const float*)d_in[8];
  const float* h_bb2  = (const float*)d_in[9];
  const float* p_w    = (const float*)d_in[10];
  const float* p_b    = (const float*)d_in[11];
  const float* p_g    = (const float*)d_in[12];
  const float* p_bb   = (const float*)d_in[13];
  const float* s_w1   = (const float*)d_in[14];
  const float* s_b1   = (const float*)d_in[15];
  const float* s_g1   = (const float*)d_in[16];
  const float* s_bb1  = (const float*)d_in[17];
  const float* s_w2   = (const float*)d_in[18];
  const float* s_b2   = (const float*)d_in[19];
  const float* s_g2   = (const float*)d_in[20];
  const float* s_bb2  = (const float*)d_in[21];
  const float* qd_w   = (const float*)d_in[22];
  const float* qd_b   = (const float*)d_in[23];
  const float* qe_w   = (const float*)d_in[24];
  const float* qe_b   = (const float*)d_in[25];

  __bf16* wsb = (__bf16*)d_ws;
  int B = in_sizes[0] / 512;
  int nblocks = B / 16;

  prep_kernel<<<(WS_ELEMS + 255) / 256, 256, 0, stream>>>(s_w1, s_w2, qd_w, qe_w, h_w1, h_w2, wsb);
  critic_kernel<<<nblocks, 512, 0, stream>>>(
      obs, pref, h_b1, h_g1, h_bb1, h_b2, h_g2, h_bb2,
      p_w, p_b, p_g, p_bb, s_b1, s_g1, s_bb1, s_b2, s_g2, s_bb2,
      qd_b, qe_b, (const __bf16*)wsb, (float*)d_out);
}